// Round 11
// baseline (560.285 us; speedup 1.0000x reference)
//
#include <hip/hip_runtime.h>
#include <stdint.h>

#define DF 128
typedef unsigned short ushort_t;
typedef __attribute__((ext_vector_type(8))) short short8v;   // 8 bf16 (4 VGPRs)
typedef __attribute__((ext_vector_type(4))) float f32x4;

// ---------------- Threefry-2x32 (JAX-compatible, 20 rounds) ----------------
__host__ __device__ __forceinline__ unsigned rotl32(unsigned v, int r) {
  return __builtin_rotateleft32(v, (unsigned)r);   // fshl -> v_alignbit_b32
}

__host__ __device__ __forceinline__ void threefry2x32(
    unsigned k0, unsigned k1, unsigned c0, unsigned c1,
    unsigned& o0, unsigned& o1) {
  unsigned kx = k0 ^ k1 ^ 0x1BD11BDAu;
  unsigned x0 = c0 + k0;
  unsigned x1 = c1 + k1;
#define TF_R(r) { x0 += x1; x1 = rotl32(x1, r); x1 ^= x0; }
  TF_R(13) TF_R(15) TF_R(26) TF_R(6)
  x0 += k1; x1 += kx + 1u;
  TF_R(17) TF_R(29) TF_R(16) TF_R(24)
  x0 += kx; x1 += k0 + 2u;
  TF_R(13) TF_R(15) TF_R(26) TF_R(6)
  x0 += k0; x1 += k1 + 3u;
  TF_R(17) TF_R(29) TF_R(16) TF_R(24)
  x0 += k1; x1 += kx + 4u;
  TF_R(13) TF_R(15) TF_R(26) TF_R(6)
  x0 += kx; x1 += k0 + 5u;
#undef TF_R
  o0 = x0; o1 = x1;
}

// 4 independent threefry chains, explicitly interleaved (ILP=4) for counters
// cb+0..cb+3 (c0=0). Returns o0^o1 per chain.
__device__ __forceinline__ void threefry4x(
    unsigned k0, unsigned k1, unsigned cb, unsigned bits[4]) {
  const unsigned kx = k0 ^ k1 ^ 0x1BD11BDAu;
  unsigned x0a = k0, x0b = k0, x0c = k0, x0d = k0;          // 0 + k0
  unsigned x1a = cb + k1, x1b = cb + 1u + k1;
  unsigned x1c = cb + 2u + k1, x1d = cb + 3u + k1;
#define TF4_R(r)                                                         \
  x0a += x1a; x0b += x1b; x0c += x1c; x0d += x1d;                        \
  x1a = rotl32(x1a, r); x1b = rotl32(x1b, r);                            \
  x1c = rotl32(x1c, r); x1d = rotl32(x1d, r);                            \
  x1a ^= x0a; x1b ^= x0b; x1c ^= x0c; x1d ^= x0d;
#define TF4_INJ(a0, a1)                                                  \
  x0a += (a0); x0b += (a0); x0c += (a0); x0d += (a0);                    \
  x1a += (a1); x1b += (a1); x1c += (a1); x1d += (a1);
  TF4_R(13) TF4_R(15) TF4_R(26) TF4_R(6)
  TF4_INJ(k1, kx + 1u)
  TF4_R(17) TF4_R(29) TF4_R(16) TF4_R(24)
  TF4_INJ(kx, k0 + 2u)
  TF4_R(13) TF4_R(15) TF4_R(26) TF4_R(6)
  TF4_INJ(k0, k1 + 3u)
  TF4_R(17) TF4_R(29) TF4_R(16) TF4_R(24)
  TF4_INJ(k1, kx + 4u)
  TF4_R(13) TF4_R(15) TF4_R(26) TF4_R(6)
  TF4_INJ(kx, k0 + 5u)
#undef TF4_R
#undef TF4_INJ
  bits[0] = x0a ^ x1a;
  bits[1] = x0b ^ x1b;
  bits[2] = x0c ^ x1c;
  bits[3] = x0d ^ x1d;
}

#define KEEP_THR 0xE6666600u   // uniform(bits) < 0.9f

// ---------------- bf16 helpers (RTNE) --------------------------------------
__device__ __forceinline__ ushort_t f2bf(float f) {
  unsigned u = __float_as_uint(f);
  unsigned r = (u + 0x7fffu + ((u >> 16) & 1u)) >> 16;
  return (ushort_t)r;
}
__device__ __forceinline__ float bf2f(unsigned h) {
  return __uint_as_float(h << 16);
}
__device__ __forceinline__ unsigned umin_u(unsigned a, unsigned b) {
  return a < b ? a : b;
}

// =================== GEMM core ==============================================
// MFMA 16x16x32 bf16; C/D: col=lane&15, row=(lane>>4)*4+j.
#define WT(k, c) sm_u[(k) * 136 + (c)]
#define CTB(r, c) sm_u[(r) * 144 + (c)]       // bf16 repack (EPI0)
#define CTF(r, c) sm_f[(r) * 68 + (c)]        // f32 repack (col-half)

__device__ __forceinline__ void gemm_core(
    const float* __restrict__ X, const float* __restrict__ W1,
    const float* __restrict__ W2, bool sumW, int M, int rbase,
    ushort_t* sm_u, f32x4 acc[2][8]) {
  const int t = threadIdx.x;
  const int lane = t & 63;
  const int w = t >> 6;
  const int lr = lane & 15;
  const int kg = lane >> 4;

#pragma unroll
  for (int i = 0; i < 16; ++i) {
    int q = t + i * 256;
    int k = q >> 5;
    int c4 = (q & 31) * 4;
    float4 wv = *reinterpret_cast<const float4*>(&W1[k * DF + c4]);
    if (sumW) {
      float4 w2 = *reinterpret_cast<const float4*>(&W2[k * DF + c4]);
      wv.x += w2.x; wv.y += w2.y; wv.z += w2.z; wv.w += w2.w;
    }
    WT(c4 + 0, k) = f2bf(wv.x);
    WT(c4 + 1, k) = f2bf(wv.y);
    WT(c4 + 2, k) = f2bf(wv.z);
    WT(c4 + 3, k) = f2bf(wv.w);
  }
  __syncthreads();

#pragma unroll
  for (int rg = 0; rg < 2; ++rg)
#pragma unroll
    for (int n = 0; n < 8; ++n) acc[rg][n] = (f32x4){0.f, 0.f, 0.f, 0.f};

#pragma unroll
  for (int kt = 0; kt < 4; ++kt) {
    const int kb = kt * 32 + kg * 8;
    short8v a[2];
#pragma unroll
    for (int rg = 0; rg < 2; ++rg) {
      int r = rbase + w * 32 + rg * 16 + lr;
      float4 x0 = make_float4(0.f, 0.f, 0.f, 0.f);
      float4 x1 = x0;
      if (r < M) {
        x0 = *reinterpret_cast<const float4*>(&X[(size_t)r * DF + kb]);
        x1 = *reinterpret_cast<const float4*>(&X[(size_t)r * DF + kb + 4]);
      }
      short8v av;
      av[0] = (short)f2bf(x0.x); av[1] = (short)f2bf(x0.y);
      av[2] = (short)f2bf(x0.z); av[3] = (short)f2bf(x0.w);
      av[4] = (short)f2bf(x1.x); av[5] = (short)f2bf(x1.y);
      av[6] = (short)f2bf(x1.z); av[7] = (short)f2bf(x1.w);
      a[rg] = av;
    }
#pragma unroll
    for (int n = 0; n < 8; ++n) {
      short8v b = *reinterpret_cast<const short8v*>(&WT(n * 16 + lr, kb));
#pragma unroll
      for (int rg = 0; rg < 2; ++rg)
        acc[rg][n] = __builtin_amdgcn_mfma_f32_16x16x32_bf16(a[rg], b, acc[rg][n], 0, 0, 0);
    }
  }
}

// ---------------- fused: 3 source-projection GEMMs + edge histogram --------
__global__ __launch_bounds__(256) void proj3_hist(
    const float* __restrict__ x_user, const float* __restrict__ x_spot,
    const float* __restrict__ Wv, const float* __restrict__ Wr,
    const float* __restrict__ Wn, int n_user, int n_spot,
    ushort_t* __restrict__ pv, ushort_t* __restrict__ pr,
    ushort_t* __restrict__ pn, int gbU, int gbS,
    const int* __restrict__ vd, const int* __restrict__ rd,
    const int* __restrict__ nd, unsigned* __restrict__ deg_all,
    int Ev, int Er, int En, int segU, int segN, int gemmBlocks) {
  __shared__ __align__(16) ushort_t sm_u[18432];   // 36864 B
  const int b = blockIdx.x;

  if (b >= gemmBlocks) {
    int i = (b - gemmBlocks) * 256 + threadIdx.x;
    if (i < Ev) atomicAdd(&deg_all[vd[i]], 1u);
    else if (i < Ev + Er) atomicAdd(&deg_all[segU + rd[i - Ev]], 1u);
    else if (i < Ev + Er + En) atomicAdd(&deg_all[segN + nd[i - Ev - Er]], 1u);
    return;
  }

  const float* X; const float* W; ushort_t* out; int M; int rbase;
  if (b < gbU)            { X = x_user; W = Wv; out = pv; M = n_user; rbase = b * 128; }
  else if (b < gbU + gbS) { X = x_spot; W = Wr; out = pr; M = n_spot; rbase = (b - gbU) * 128; }
  else                    { X = x_spot; W = Wn; out = pn; M = n_spot; rbase = (b - gbU - gbS) * 128; }

  f32x4 acc[2][8];
  gemm_core(X, W, nullptr, false, M, rbase, sm_u, acc);

  const int t = threadIdx.x;
  const int lane = t & 63;
  const int w = t >> 6;
  const int lr = lane & 15;
  const int kg = lane >> 4;

  __syncthreads();
#pragma unroll
  for (int rg = 0; rg < 2; ++rg) {
    const int rowb = w * 32 + rg * 16 + kg * 4;
#pragma unroll
    for (int n = 0; n < 8; ++n) {
      const int col = n * 16 + lr;
#pragma unroll
      for (int j = 0; j < 4; ++j) CTB(rowb + j, col) = f2bf(acc[rg][n][j]);
    }
  }
  __syncthreads();
#pragma unroll
  for (int i = 0; i < 8; ++i) {
    const int u = t + i * 256;
    const int row = u >> 4, ch = u & 15;
    const int grow = rbase + row;
    if (grow < M)
      *reinterpret_cast<uint4*>(&out[(size_t)grow * DF + ch * 8]) =
          *reinterpret_cast<const uint4*>(&CTB(row, ch * 8));
  }
}

// ---------------- fused finalize GEMM (EPI1 user / EPI2 spot) ---------------
__global__ __launch_bounds__(256) void final2_gemm(
    const float* __restrict__ x_user, const float* __restrict__ x_spot,
    const float* __restrict__ Wrt, const float* __restrict__ Wvt,
    const float* __restrict__ Wnt, int n_user, int n_spot,
    float* __restrict__ out_user, float* __restrict__ out_spot,
    const ushort_t* __restrict__ mean_u, const ushort_t* __restrict__ mean_sv,
    const ushort_t* __restrict__ mean_sn, int gbU) {
  __shared__ __align__(16) ushort_t sm_u[17408];
  float* sm_f_raw = reinterpret_cast<float*>(sm_u);
#define sm_f sm_f_raw
  const int b = blockIdx.x;
  const bool epi2 = (b >= gbU);
  const float* X; const float* W1; const float* W2; float* outF;
  const ushort_t* m1; const ushort_t* m2; int M; int rbase;
  if (!epi2) {
    X = x_user; W1 = Wrt; W2 = nullptr; outF = out_user;
    m1 = mean_u; m2 = nullptr; M = n_user; rbase = b * 128;
  } else {
    X = x_spot; W1 = Wvt; W2 = Wnt; outF = out_spot;
    m1 = mean_sv; m2 = mean_sn; M = n_spot; rbase = (b - gbU) * 128;
  }

  f32x4 acc[2][8];
  gemm_core(X, W1, W2, epi2, M, rbase, sm_u, acc);

  const int t = threadIdx.x;
  const int lane = t & 63;
  const int w = t >> 6;
  const int lr = lane & 15;
  const int kg = lane >> 4;

#pragma unroll
  for (int h = 0; h < 2; ++h) {
    __syncthreads();
#pragma unroll
    for (int rg = 0; rg < 2; ++rg) {
      const int rowb = w * 32 + rg * 16 + kg * 4;
#pragma unroll
      for (int n2 = 0; n2 < 4; ++n2) {
        const int n = h * 4 + n2;
        const int col = n2 * 16 + lr;
#pragma unroll
        for (int j = 0; j < 4; ++j) CTF(rowb + j, col) = acc[rg][n][j];
      }
    }
    __syncthreads();
#pragma unroll
    for (int i = 0; i < 8; ++i) {
      const int u = t + i * 256;
      const int row = u >> 4;
      const int c4 = (u & 15) * 4;
      const int grow = rbase + row;
      if (grow < M) {
        const float4 vv = *reinterpret_cast<const float4*>(&CTF(row, c4));
        const int col = h * 64 + c4;
        const uint2 mb = *reinterpret_cast<const uint2*>(&m1[(size_t)grow * DF + col]);
        float a0 = bf2f(mb.x & 0xffffu), a1 = bf2f(mb.x >> 16);
        float a2 = bf2f(mb.y & 0xffffu), a3 = bf2f(mb.y >> 16);
        float4 r;
        if (!epi2) {
          r.x = fmaxf(vv.x + a0, 0.f);
          r.y = fmaxf(vv.y + a1, 0.f);
          r.z = fmaxf(vv.z + a2, 0.f);
          r.w = fmaxf(vv.w + a3, 0.f);
        } else {
          const uint2 nb = *reinterpret_cast<const uint2*>(&m2[(size_t)grow * DF + col]);
          r.x = fmaxf(0.5f * (vv.x + a0 + bf2f(nb.x & 0xffffu)), 0.f);
          r.y = fmaxf(0.5f * (vv.y + a1 + bf2f(nb.x >> 16)), 0.f);
          r.z = fmaxf(0.5f * (vv.z + a2 + bf2f(nb.y & 0xffffu)), 0.f);
          r.w = fmaxf(0.5f * (vv.w + a3 + bf2f(nb.y >> 16)), 0.f);
        }
        *reinterpret_cast<float4*>(&outF[(size_t)grow * DF + col]) = r;
      }
    }
  }
#undef sm_f
}

// ---- single-kernel 2-level exclusive scan (last-block pattern + spin) ------
#define SCAN_E 2048   // 256 threads x 8 elems

__global__ __launch_bounds__(256) void scanABC(
    const unsigned* __restrict__ deg, unsigned* __restrict__ bsum,
    unsigned* __restrict__ bsumX, unsigned* __restrict__ rp,
    unsigned* __restrict__ cur, unsigned* __restrict__ done,
    int NT, int nb) {
  __shared__ unsigned sm[256];
  __shared__ int amLast;
  const int t = threadIdx.x;
  const int base = blockIdx.x * SCAN_E + t * 8;
  unsigned vals[8];
  unsigned s = 0;
#pragma unroll
  for (int j = 0; j < 8; ++j) {
    int i = base + j;
    vals[j] = (i < NT) ? deg[i] : 0u;
    s += vals[j];
  }
  sm[t] = s;
  __syncthreads();
  for (int off = 1; off < 256; off <<= 1) {
    unsigned u = (t >= off) ? sm[t - off] : 0u;
    __syncthreads();
    sm[t] += u;
    __syncthreads();
  }
  const unsigned myExcl = sm[t] - s;
  const unsigned blockTotal = sm[255];

  if (t == 0) {
    bsum[blockIdx.x] = blockTotal;
    __threadfence();
    unsigned prev = atomicAdd(&done[0], 1u);
    amLast = (prev == (unsigned)(nb - 1));
  }
  __syncthreads();

  if (amLast) {
    __threadfence();
    unsigned v = (t < nb) ? bsum[t] : 0u;
    __syncthreads();
    sm[t] = v;
    __syncthreads();
    for (int off = 1; off < 256; off <<= 1) {
      unsigned u = (t >= off) ? sm[t - off] : 0u;
      __syncthreads();
      sm[t] += u;
      __syncthreads();
    }
    if (t < nb) bsumX[t] = sm[t] - v;
    if (t == nb - 1) rp[NT] = sm[t];
    __threadfence();
    if (t == 0) __hip_atomic_store(&done[1], 1u, __ATOMIC_RELEASE,
                                   __HIP_MEMORY_SCOPE_AGENT);
  }

  if (t == 0) {
    while (__hip_atomic_load(&done[1], __ATOMIC_ACQUIRE,
                             __HIP_MEMORY_SCOPE_AGENT) == 0u) {
      __builtin_amdgcn_s_sleep(8);
    }
  }
  __syncthreads();

  const unsigned bx = __hip_atomic_load(&bsumX[blockIdx.x], __ATOMIC_RELAXED,
                                        __HIP_MEMORY_SCOPE_AGENT);
  unsigned run = bx + myExcl;
#pragma unroll
  for (int j = 0; j < 8; ++j) {
    int i = base + j;
    if (i < NT) { rp[i] = run; cur[i] = run; }
    run += vals[j];
  }
}

__global__ __launch_bounds__(256) void fill3(
    const int* __restrict__ vs, const int* __restrict__ vd,
    const int* __restrict__ rs, const int* __restrict__ rd,
    const int* __restrict__ ns, const int* __restrict__ nd,
    unsigned* __restrict__ cur_all, uint2* __restrict__ es_all,
    int Ev, int Er, int En, int segU, int segN) {
  int i = blockIdx.x * 256 + threadIdx.x;
  if (i < Ev) {
    unsigned slot = atomicAdd(&cur_all[vd[i]], 1u);
    es_all[slot] = make_uint2((unsigned)i, (unsigned)vs[i]);
  } else if (i < Ev + Er) {
    int e = i - Ev;
    unsigned slot = atomicAdd(&cur_all[segU + rd[e]], 1u);
    es_all[slot] = make_uint2((unsigned)e, (unsigned)rs[e]);
  } else if (i < Ev + Er + En) {
    int e = i - Ev - Er;
    unsigned slot = atomicAdd(&cur_all[segN + nd[e]], 1u);
    es_all[slot] = make_uint2((unsigned)e, (unsigned)ns[e]);
  }
}

// ---------------- fused gather-reduce: one wave per dst row -----------------
// Round-7 structure; threefry4x (explicit 4-chain ILP) in the hot loop.
__global__ __launch_bounds__(256) void gather_reduce_all(
    const ushort_t* __restrict__ proj_v, const ushort_t* __restrict__ proj_r,
    const ushort_t* __restrict__ proj_n, const uint2* __restrict__ es,
    const unsigned* __restrict__ rp, ushort_t* __restrict__ accum_all,
    int NT, int segU, int segN, unsigned emax,
    unsigned kv0, unsigned kv1, unsigned kr0, unsigned kr1,
    unsigned kn0, unsigned kn1) {
  const int lane = threadIdx.x & 63;
  int d = blockIdx.x * 4 + (threadIdx.x >> 6);
  d = __builtin_amdgcn_readfirstlane(d);
  if (d >= NT) return;

  const ushort_t* proj;
  unsigned k0, k1;
  if (d < segU)      { proj = proj_v; k0 = kv0; k1 = kv1; }
  else if (d < segN) { proj = proj_r; k0 = kr0; k1 = kr1; }
  else               { proj = proj_n; k0 = kn0; k1 = kn1; }

  const unsigned b0 = __builtin_amdgcn_readfirstlane(rp[d]);
  const unsigned n  = __builtin_amdgcn_readfirstlane(rp[d + 1]) - b0;

  const bool hi = lane >= 32;
  const unsigned l31 = (unsigned)(lane & 31);
  const unsigned voff8 = l31 * 8u;

  const unsigned npairs = n >> 1;
  const unsigned odd = n & 1u;

  uint2 P0 = es[umin_u(b0, emax)];
  uint2 P1 = es[umin_u(b0 + 1u, emax)];
  unsigned eA = __builtin_amdgcn_readfirstlane(P0.x);
  unsigned sA = __builtin_amdgcn_readfirstlane(P0.y);
  unsigned eB = __builtin_amdgcn_readfirstlane(P1.x);
  unsigned sB = __builtin_amdgcn_readfirstlane(P1.y);

  float a0 = 0.f, a1 = 0.f, a2 = 0.f, a3 = 0.f;

  for (unsigned p = 0; p < npairs; ++p) {
    const unsigned src = hi ? sB : sA;
    const unsigned eid = hi ? eB : eA;
    const uint2 g = *reinterpret_cast<const uint2*>(
        reinterpret_cast<const char*>(proj) + ((size_t)src << 8) + voff8);
    uint2 Pn0 = es[umin_u(b0 + 2u * p + 2u, emax)];
    uint2 Pn1 = es[umin_u(b0 + 2u * p + 3u, emax)];

    const unsigned cb = eid * 128u + l31 * 4u;
    unsigned bits[4];
    threefry4x(k0, k1, cb, bits);
    const float m0 = (bits[0] < KEEP_THR) ? (1.0f / 0.9f) : 0.f;
    const float m1 = (bits[1] < KEEP_THR) ? (1.0f / 0.9f) : 0.f;
    const float m2 = (bits[2] < KEEP_THR) ? (1.0f / 0.9f) : 0.f;
    const float m3 = (bits[3] < KEEP_THR) ? (1.0f / 0.9f) : 0.f;
    a0 = fmaf(__uint_as_float(g.x << 16), m0, a0);
    a1 = fmaf(__uint_as_float(g.x & 0xffff0000u), m1, a1);
    a2 = fmaf(__uint_as_float(g.y << 16), m2, a2);
    a3 = fmaf(__uint_as_float(g.y & 0xffff0000u), m3, a3);

    eA = __builtin_amdgcn_readfirstlane(Pn0.x);
    sA = __builtin_amdgcn_readfirstlane(Pn0.y);
    eB = __builtin_amdgcn_readfirstlane(Pn1.x);
    sB = __builtin_amdgcn_readfirstlane(Pn1.y);
  }

  if (odd) {
    const uint2 g = *reinterpret_cast<const uint2*>(
        reinterpret_cast<const char*>(proj) + ((size_t)sA << 8) + voff8);
    const unsigned cb = eA * 128u + l31 * 4u;
    unsigned bits[4];
    threefry4x(k0, k1, cb, bits);
    const float sc = hi ? 0.f : (1.0f / 0.9f);
    const float m0 = (bits[0] < KEEP_THR) ? sc : 0.f;
    const float m1 = (bits[1] < KEEP_THR) ? sc : 0.f;
    const float m2 = (bits[2] < KEEP_THR) ? sc : 0.f;
    const float m3 = (bits[3] < KEEP_THR) ? sc : 0.f;
    a0 = fmaf(__uint_as_float(g.x << 16), m0, a0);
    a1 = fmaf(__uint_as_float(g.x & 0xffff0000u), m1, a1);
    a2 = fmaf(__uint_as_float(g.y << 16), m2, a2);
    a3 = fmaf(__uint_as_float(g.y & 0xffff0000u), m3, a3);
  }

  a0 += __shfl_xor(a0, 32);
  a1 += __shfl_xor(a1, 32);
  a2 += __shfl_xor(a2, 32);
  a3 += __shfl_xor(a3, 32);

  const float inv = 1.0f / fmaxf((float)n, 1.0f);
  const float u0 = hi ? a2 : a0;
  const float u1 = hi ? a3 : a1;
  const unsigned pk =
      ((unsigned)f2bf(u0 * inv)) | (((unsigned)f2bf(u1 * inv)) << 16);
  unsigned* out = reinterpret_cast<unsigned*>(accum_all) + (size_t)d * 64;
  out[2u * l31 + (hi ? 1u : 0u)] = pk;
}

// ---------------------------------------------------------------------------
extern "C" void kernel_launch(void* const* d_in, const int* in_sizes, int n_in,
                              void* d_out, int out_size, void* d_ws, size_t ws_size,
                              hipStream_t stream) {
  const float* x_user      = (const float*)d_in[0];
  const float* x_spot      = (const float*)d_in[1];
  const float* W_visit_src = (const float*)d_in[2];
  const float* W_visit_tgt = (const float*)d_in[3];
  const float* W_rev_src   = (const float*)d_in[4];
  const float* W_rev_tgt   = (const float*)d_in[5];
  const float* W_near_src  = (const float*)d_in[6];
  const float* W_near_tgt  = (const float*)d_in[7];
  const int* visit_src = (const int*)d_in[8];
  const int* visit_dst = (const int*)d_in[9];
  const int* rev_src   = (const int*)d_in[10];
  const int* rev_dst   = (const int*)d_in[11];
  const int* near_src  = (const int*)d_in[12];
  const int* near_dst  = (const int*)d_in[13];

  const int n_user = in_sizes[0] / DF;
  const int n_spot = in_sizes[1] / DF;
  const int e_visit = in_sizes[8];
  const int e_rev   = in_sizes[10];
  const int e_near  = in_sizes[12];

  float* out_user = (float*)d_out;
  float* out_spot = out_user + (size_t)n_user * DF;

  const int NT = n_spot + n_user + n_spot;
  const int segU = n_spot;
  const int segN = n_spot + n_user;
  const int etot = e_visit + e_rev + e_near;
  const unsigned emax = (unsigned)(etot - 1);

  // ---- workspace ----
  char* ws = (char*)d_ws;
  size_t off = 0;
  auto alloc = [&](size_t bytes) -> void* {
    void* p = ws + off;
    off += (bytes + 255) & ~(size_t)255;
    return p;
  };
  ushort_t* proj_vs   = (ushort_t*)alloc((size_t)n_user * DF * 2);
  ushort_t* proj_rs   = (ushort_t*)alloc((size_t)n_spot * DF * 2);
  ushort_t* proj_ns   = (ushort_t*)alloc((size_t)n_spot * DF * 2);
  ushort_t* accum_all = (ushort_t*)alloc((size_t)NT * DF * 2);
  uint2*    es_all    = (uint2*)   alloc((size_t)etot * 8);
  unsigned* rp_all    = (unsigned*)alloc(((size_t)NT + 1) * 4);
  unsigned* cur_all   = (unsigned*)alloc((size_t)NT * 4);
  unsigned* deg_all   = (unsigned*)alloc((size_t)NT * 4);
  unsigned* done      = (unsigned*)alloc(256);    // done[0]=counter, done[1]=flag
  unsigned* bsum      = (unsigned*)alloc(4096);
  unsigned* bsumX     = (unsigned*)alloc(4096);
  char* zero_end = (char*)bsum;   // memset deg_all..done (contiguous)

  ushort_t* mean_sv = accum_all;
  ushort_t* mean_u  = accum_all + (size_t)segU * DF;
  ushort_t* mean_sn = accum_all + (size_t)segN * DF;

  unsigned kv0, kv1, kr0, kr1, kn0, kn1;
  threefry2x32(0u, 1u, 0u, 0u, kv0, kv1);
  threefry2x32(0u, 1u, 0u, 1u, kr0, kr1);
  threefry2x32(0u, 1u, 0u, 2u, kn0, kn1);

  dim3 blk(256);
  const int gbU = (n_user + 127) / 128;
  const int gbS = (n_spot + 127) / 128;
  const int gb_e = (etot + 255) / 256;
  const int nb_scan = (NT + SCAN_E - 1) / SCAN_E;
  const int gemmBlocks = gbU + 2 * gbS;

  // zero deg_all + done counters (contiguous region)
  hipMemsetAsync(deg_all, 0, (size_t)(zero_end - (char*)deg_all), stream);

  // fused: 3 projection GEMMs + edge histogram (overlapping block roles)
  proj3_hist<<<gemmBlocks + gb_e, blk, 0, stream>>>(
      x_user, x_spot, W_visit_src, W_rev_src, W_near_src,
      n_user, n_spot, proj_vs, proj_rs, proj_ns, gbU, gbS,
      visit_dst, rev_dst, near_dst, deg_all,
      e_visit, e_rev, e_near, segU, segN, gemmBlocks);

  // single-kernel 2-level scan -> rowptr + cursors
  scanABC<<<nb_scan, blk, 0, stream>>>(deg_all, bsum, bsumX, rp_all, cur_all,
                                       done, NT, nb_scan);
  fill3<<<gb_e, blk, 0, stream>>>(visit_src, visit_dst, rev_src, rev_dst,
                                  near_src, near_dst, cur_all, es_all,
                                  e_visit, e_rev, e_near, segU, segN);

  // fused gather-reduce over all NT rows
  gather_reduce_all<<<(NT + 3) / 4, blk, 0, stream>>>(
      proj_vs, proj_rs, proj_ns, es_all, rp_all, accum_all,
      NT, segU, segN, emax, kv0, kv1, kr0, kr1, kn0, kn1);

  // fused finalize
  final2_gemm<<<gbU + gbS, blk, 0, stream>>>(
      x_user, x_spot, W_rev_tgt, W_visit_tgt, W_near_tgt,
      n_user, n_spot, out_user, out_spot, mean_u, mean_sv, mean_sn, gbU);
}

// Round 12
// 528.489 us; speedup vs baseline: 1.0602x; 1.0602x over previous
//
#include <hip/hip_runtime.h>
#include <stdint.h>

#define DF 128
typedef unsigned short ushort_t;
typedef __attribute__((ext_vector_type(8))) short short8v;   // 8 bf16 (4 VGPRs)
typedef __attribute__((ext_vector_type(4))) float f32x4;

// ---------------- Threefry-2x32 (JAX-compatible, 20 rounds) ----------------
__host__ __device__ __forceinline__ unsigned rotl32(unsigned v, int r) {
  return __builtin_rotateleft32(v, (unsigned)r);   // fshl -> v_alignbit_b32
}

__host__ __device__ __forceinline__ void threefry2x32(
    unsigned k0, unsigned k1, unsigned c0, unsigned c1,
    unsigned& o0, unsigned& o1) {
  unsigned kx = k0 ^ k1 ^ 0x1BD11BDAu;
  unsigned x0 = c0 + k0;
  unsigned x1 = c1 + k1;
#define TF_R(r) { x0 += x1; x1 = rotl32(x1, r); x1 ^= x0; }
  TF_R(13) TF_R(15) TF_R(26) TF_R(6)
  x0 += k1; x1 += kx + 1u;
  TF_R(17) TF_R(29) TF_R(16) TF_R(24)
  x0 += kx; x1 += k0 + 2u;
  TF_R(13) TF_R(15) TF_R(26) TF_R(6)
  x0 += k0; x1 += k1 + 3u;
  TF_R(17) TF_R(29) TF_R(16) TF_R(24)
  x0 += k1; x1 += kx + 4u;
  TF_R(13) TF_R(15) TF_R(26) TF_R(6)
  x0 += kx; x1 += k0 + 5u;
#undef TF_R
  o0 = x0; o1 = x1;
}

#define KEEP_THR 0xE6666600u   // uniform(bits) < 0.9f

// ---------------- bf16 helpers (RTNE) --------------------------------------
__device__ __forceinline__ ushort_t f2bf(float f) {
  unsigned u = __float_as_uint(f);
  unsigned r = (u + 0x7fffu + ((u >> 16) & 1u)) >> 16;
  return (ushort_t)r;
}
__device__ __forceinline__ float bf2f(unsigned h) {
  return __uint_as_float(h << 16);
}
__device__ __forceinline__ unsigned umin_u(unsigned a, unsigned b) {
  return a < b ? a : b;
}

// =================== GEMM core ==============================================
// MFMA 16x16x32 bf16; C/D: col=lane&15, row=(lane>>4)*4+j.
#define WT(k, c) sm_u[(k) * 136 + (c)]
#define CTB(r, c) sm_u[(r) * 144 + (c)]       // bf16 repack (EPI0)
#define CTF(r, c) sm_f[(r) * 68 + (c)]        // f32 repack (col-half)

__device__ __forceinline__ void gemm_core(
    const float* __restrict__ X, const float* __restrict__ W1,
    const float* __restrict__ W2, bool sumW, int M, int rbase,
    ushort_t* sm_u, f32x4 acc[2][8]) {
  const int t = threadIdx.x;
  const int lane = t & 63;
  const int w = t >> 6;
  const int lr = lane & 15;
  const int kg = lane >> 4;

#pragma unroll
  for (int i = 0; i < 16; ++i) {
    int q = t + i * 256;
    int k = q >> 5;
    int c4 = (q & 31) * 4;
    float4 wv = *reinterpret_cast<const float4*>(&W1[k * DF + c4]);
    if (sumW) {
      float4 w2 = *reinterpret_cast<const float4*>(&W2[k * DF + c4]);
      wv.x += w2.x; wv.y += w2.y; wv.z += w2.z; wv.w += w2.w;
    }
    WT(c4 + 0, k) = f2bf(wv.x);
    WT(c4 + 1, k) = f2bf(wv.y);
    WT(c4 + 2, k) = f2bf(wv.z);
    WT(c4 + 3, k) = f2bf(wv.w);
  }
  __syncthreads();

#pragma unroll
  for (int rg = 0; rg < 2; ++rg)
#pragma unroll
    for (int n = 0; n < 8; ++n) acc[rg][n] = (f32x4){0.f, 0.f, 0.f, 0.f};

#pragma unroll
  for (int kt = 0; kt < 4; ++kt) {
    const int kb = kt * 32 + kg * 8;
    short8v a[2];
#pragma unroll
    for (int rg = 0; rg < 2; ++rg) {
      int r = rbase + w * 32 + rg * 16 + lr;
      float4 x0 = make_float4(0.f, 0.f, 0.f, 0.f);
      float4 x1 = x0;
      if (r < M) {
        x0 = *reinterpret_cast<const float4*>(&X[(size_t)r * DF + kb]);
        x1 = *reinterpret_cast<const float4*>(&X[(size_t)r * DF + kb + 4]);
      }
      short8v av;
      av[0] = (short)f2bf(x0.x); av[1] = (short)f2bf(x0.y);
      av[2] = (short)f2bf(x0.z); av[3] = (short)f2bf(x0.w);
      av[4] = (short)f2bf(x1.x); av[5] = (short)f2bf(x1.y);
      av[6] = (short)f2bf(x1.z); av[7] = (short)f2bf(x1.w);
      a[rg] = av;
    }
#pragma unroll
    for (int n = 0; n < 8; ++n) {
      short8v b = *reinterpret_cast<const short8v*>(&WT(n * 16 + lr, kb));
#pragma unroll
      for (int rg = 0; rg < 2; ++rg)
        acc[rg][n] = __builtin_amdgcn_mfma_f32_16x16x32_bf16(a[rg], b, acc[rg][n], 0, 0, 0);
    }
  }
}

// ---------------- fused: 3 source-projection GEMMs + edge histogram --------
__global__ __launch_bounds__(256) void proj3_hist(
    const float* __restrict__ x_user, const float* __restrict__ x_spot,
    const float* __restrict__ Wv, const float* __restrict__ Wr,
    const float* __restrict__ Wn, int n_user, int n_spot,
    ushort_t* __restrict__ pv, ushort_t* __restrict__ pr,
    ushort_t* __restrict__ pn, int gbU, int gbS,
    const int* __restrict__ vd, const int* __restrict__ rd,
    const int* __restrict__ nd, unsigned* __restrict__ deg_all,
    int Ev, int Er, int En, int segU, int segN, int gemmBlocks) {
  __shared__ __align__(16) ushort_t sm_u[18432];   // 36864 B
  const int b = blockIdx.x;

  if (b >= gemmBlocks) {
    int i = (b - gemmBlocks) * 256 + threadIdx.x;
    if (i < Ev) atomicAdd(&deg_all[vd[i]], 1u);
    else if (i < Ev + Er) atomicAdd(&deg_all[segU + rd[i - Ev]], 1u);
    else if (i < Ev + Er + En) atomicAdd(&deg_all[segN + nd[i - Ev - Er]], 1u);
    return;
  }

  const float* X; const float* W; ushort_t* out; int M; int rbase;
  if (b < gbU)            { X = x_user; W = Wv; out = pv; M = n_user; rbase = b * 128; }
  else if (b < gbU + gbS) { X = x_spot; W = Wr; out = pr; M = n_spot; rbase = (b - gbU) * 128; }
  else                    { X = x_spot; W = Wn; out = pn; M = n_spot; rbase = (b - gbU - gbS) * 128; }

  f32x4 acc[2][8];
  gemm_core(X, W, nullptr, false, M, rbase, sm_u, acc);

  const int t = threadIdx.x;
  const int lane = t & 63;
  const int w = t >> 6;
  const int lr = lane & 15;
  const int kg = lane >> 4;

  __syncthreads();
#pragma unroll
  for (int rg = 0; rg < 2; ++rg) {
    const int rowb = w * 32 + rg * 16 + kg * 4;
#pragma unroll
    for (int n = 0; n < 8; ++n) {
      const int col = n * 16 + lr;
#pragma unroll
      for (int j = 0; j < 4; ++j) CTB(rowb + j, col) = f2bf(acc[rg][n][j]);
    }
  }
  __syncthreads();
#pragma unroll
  for (int i = 0; i < 8; ++i) {
    const int u = t + i * 256;
    const int row = u >> 4, ch = u & 15;
    const int grow = rbase + row;
    if (grow < M)
      *reinterpret_cast<uint4*>(&out[(size_t)grow * DF + ch * 8]) =
          *reinterpret_cast<const uint4*>(&CTB(row, ch * 8));
  }
}

// ---------------- fused finalize GEMM (EPI1 user / EPI2 spot) ---------------
__global__ __launch_bounds__(256) void final2_gemm(
    const float* __restrict__ x_user, const float* __restrict__ x_spot,
    const float* __restrict__ Wrt, const float* __restrict__ Wvt,
    const float* __restrict__ Wnt, int n_user, int n_spot,
    float* __restrict__ out_user, float* __restrict__ out_spot,
    const ushort_t* __restrict__ mean_u, const ushort_t* __restrict__ mean_sv,
    const ushort_t* __restrict__ mean_sn, int gbU) {
  __shared__ __align__(16) ushort_t sm_u[17408];
  float* sm_f_raw = reinterpret_cast<float*>(sm_u);
#define sm_f sm_f_raw
  const int b = blockIdx.x;
  const bool epi2 = (b >= gbU);
  const float* X; const float* W1; const float* W2; float* outF;
  const ushort_t* m1; const ushort_t* m2; int M; int rbase;
  if (!epi2) {
    X = x_user; W1 = Wrt; W2 = nullptr; outF = out_user;
    m1 = mean_u; m2 = nullptr; M = n_user; rbase = b * 128;
  } else {
    X = x_spot; W1 = Wvt; W2 = Wnt; outF = out_spot;
    m1 = mean_sv; m2 = mean_sn; M = n_spot; rbase = (b - gbU) * 128;
  }

  f32x4 acc[2][8];
  gemm_core(X, W1, W2, epi2, M, rbase, sm_u, acc);

  const int t = threadIdx.x;
  const int lane = t & 63;
  const int w = t >> 6;
  const int lr = lane & 15;
  const int kg = lane >> 4;

#pragma unroll
  for (int h = 0; h < 2; ++h) {
    __syncthreads();
#pragma unroll
    for (int rg = 0; rg < 2; ++rg) {
      const int rowb = w * 32 + rg * 16 + kg * 4;
#pragma unroll
      for (int n2 = 0; n2 < 4; ++n2) {
        const int n = h * 4 + n2;
        const int col = n2 * 16 + lr;
#pragma unroll
        for (int j = 0; j < 4; ++j) CTF(rowb + j, col) = acc[rg][n][j];
      }
    }
    __syncthreads();
#pragma unroll
    for (int i = 0; i < 8; ++i) {
      const int u = t + i * 256;
      const int row = u >> 4;
      const int c4 = (u & 15) * 4;
      const int grow = rbase + row;
      if (grow < M) {
        const float4 vv = *reinterpret_cast<const float4*>(&CTF(row, c4));
        const int col = h * 64 + c4;
        const uint2 mb = *reinterpret_cast<const uint2*>(&m1[(size_t)grow * DF + col]);
        float a0 = bf2f(mb.x & 0xffffu), a1 = bf2f(mb.x >> 16);
        float a2 = bf2f(mb.y & 0xffffu), a3 = bf2f(mb.y >> 16);
        float4 r;
        if (!epi2) {
          r.x = fmaxf(vv.x + a0, 0.f);
          r.y = fmaxf(vv.y + a1, 0.f);
          r.z = fmaxf(vv.z + a2, 0.f);
          r.w = fmaxf(vv.w + a3, 0.f);
        } else {
          const uint2 nb = *reinterpret_cast<const uint2*>(&m2[(size_t)grow * DF + col]);
          r.x = fmaxf(0.5f * (vv.x + a0 + bf2f(nb.x & 0xffffu)), 0.f);
          r.y = fmaxf(0.5f * (vv.y + a1 + bf2f(nb.x >> 16)), 0.f);
          r.z = fmaxf(0.5f * (vv.z + a2 + bf2f(nb.y & 0xffffu)), 0.f);
          r.w = fmaxf(0.5f * (vv.w + a3 + bf2f(nb.y >> 16)), 0.f);
        }
        *reinterpret_cast<float4*>(&outF[(size_t)grow * DF + col]) = r;
      }
    }
  }
#undef sm_f
}

// ---- single-kernel 2-level exclusive scan (last-block pattern + spin) ------
#define SCAN_E 2048   // 256 threads x 8 elems

__global__ __launch_bounds__(256) void scanABC(
    const unsigned* __restrict__ deg, unsigned* __restrict__ bsum,
    unsigned* __restrict__ bsumX, unsigned* __restrict__ rp,
    unsigned* __restrict__ cur, unsigned* __restrict__ done,
    int NT, int nb) {
  __shared__ unsigned sm[256];
  __shared__ int amLast;
  const int t = threadIdx.x;
  const int base = blockIdx.x * SCAN_E + t * 8;
  unsigned vals[8];
  unsigned s = 0;
#pragma unroll
  for (int j = 0; j < 8; ++j) {
    int i = base + j;
    vals[j] = (i < NT) ? deg[i] : 0u;
    s += vals[j];
  }
  sm[t] = s;
  __syncthreads();
  for (int off = 1; off < 256; off <<= 1) {
    unsigned u = (t >= off) ? sm[t - off] : 0u;
    __syncthreads();
    sm[t] += u;
    __syncthreads();
  }
  const unsigned myExcl = sm[t] - s;
  const unsigned blockTotal = sm[255];

  if (t == 0) {
    bsum[blockIdx.x] = blockTotal;
    __threadfence();
    unsigned prev = atomicAdd(&done[0], 1u);
    amLast = (prev == (unsigned)(nb - 1));
  }
  __syncthreads();

  if (amLast) {
    __threadfence();
    unsigned v = (t < nb) ? bsum[t] : 0u;
    __syncthreads();
    sm[t] = v;
    __syncthreads();
    for (int off = 1; off < 256; off <<= 1) {
      unsigned u = (t >= off) ? sm[t - off] : 0u;
      __syncthreads();
      sm[t] += u;
      __syncthreads();
    }
    if (t < nb) bsumX[t] = sm[t] - v;
    if (t == nb - 1) rp[NT] = sm[t];
    __threadfence();
    if (t == 0) __hip_atomic_store(&done[1], 1u, __ATOMIC_RELEASE,
                                   __HIP_MEMORY_SCOPE_AGENT);
  }

  if (t == 0) {
    while (__hip_atomic_load(&done[1], __ATOMIC_ACQUIRE,
                             __HIP_MEMORY_SCOPE_AGENT) == 0u) {
      __builtin_amdgcn_s_sleep(8);
    }
  }
  __syncthreads();

  const unsigned bx = __hip_atomic_load(&bsumX[blockIdx.x], __ATOMIC_RELAXED,
                                        __HIP_MEMORY_SCOPE_AGENT);
  unsigned run = bx + myExcl;
#pragma unroll
  for (int j = 0; j < 8; ++j) {
    int i = base + j;
    if (i < NT) { rp[i] = run; cur[i] = run; }
    run += vals[j];
  }
}

__global__ __launch_bounds__(256) void fill3(
    const int* __restrict__ vs, const int* __restrict__ vd,
    const int* __restrict__ rs, const int* __restrict__ rd,
    const int* __restrict__ ns, const int* __restrict__ nd,
    unsigned* __restrict__ cur_all, uint2* __restrict__ es_all,
    int Ev, int Er, int En, int segU, int segN) {
  int i = blockIdx.x * 256 + threadIdx.x;
  if (i < Ev) {
    unsigned slot = atomicAdd(&cur_all[vd[i]], 1u);
    es_all[slot] = make_uint2((unsigned)i, (unsigned)vs[i]);
  } else if (i < Ev + Er) {
    int e = i - Ev;
    unsigned slot = atomicAdd(&cur_all[segU + rd[e]], 1u);
    es_all[slot] = make_uint2((unsigned)e, (unsigned)rs[e]);
  } else if (i < Ev + Er + En) {
    int e = i - Ev - Er;
    unsigned slot = atomicAdd(&cur_all[segN + nd[e]], 1u);
    es_all[slot] = make_uint2((unsigned)e, (unsigned)ns[e]);
  }
}

// ---------------- fused gather-reduce: one wave per dst row -----------------
// Round-7 structure (empirical optimum): lanes 0-31 edge i, lanes 32-63 edge
// i+1; scalar (readfirstlane) es pipeline; dwordx2 gather; shfl_xor combine.
__global__ __launch_bounds__(256) void gather_reduce_all(
    const ushort_t* __restrict__ proj_v, const ushort_t* __restrict__ proj_r,
    const ushort_t* __restrict__ proj_n, const uint2* __restrict__ es,
    const unsigned* __restrict__ rp, ushort_t* __restrict__ accum_all,
    int NT, int segU, int segN, unsigned emax,
    unsigned kv0, unsigned kv1, unsigned kr0, unsigned kr1,
    unsigned kn0, unsigned kn1) {
  const int lane = threadIdx.x & 63;
  int d = blockIdx.x * 4 + (threadIdx.x >> 6);
  d = __builtin_amdgcn_readfirstlane(d);
  if (d >= NT) return;

  const ushort_t* proj;
  unsigned k0, k1;
  if (d < segU)      { proj = proj_v; k0 = kv0; k1 = kv1; }
  else if (d < segN) { proj = proj_r; k0 = kr0; k1 = kr1; }
  else               { proj = proj_n; k0 = kn0; k1 = kn1; }

  const unsigned b0 = __builtin_amdgcn_readfirstlane(rp[d]);
  const unsigned n  = __builtin_amdgcn_readfirstlane(rp[d + 1]) - b0;

  const bool hi = lane >= 32;
  const unsigned l31 = (unsigned)(lane & 31);
  const unsigned voff8 = l31 * 8u;

  const unsigned npairs = n >> 1;
  const unsigned odd = n & 1u;

  uint2 P0 = es[umin_u(b0, emax)];
  uint2 P1 = es[umin_u(b0 + 1u, emax)];
  unsigned eA = __builtin_amdgcn_readfirstlane(P0.x);
  unsigned sA = __builtin_amdgcn_readfirstlane(P0.y);
  unsigned eB = __builtin_amdgcn_readfirstlane(P1.x);
  unsigned sB = __builtin_amdgcn_readfirstlane(P1.y);

  float a0 = 0.f, a1 = 0.f, a2 = 0.f, a3 = 0.f;

  for (unsigned p = 0; p < npairs; ++p) {
    const unsigned src = hi ? sB : sA;
    const unsigned eid = hi ? eB : eA;
    const uint2 g = *reinterpret_cast<const uint2*>(
        reinterpret_cast<const char*>(proj) + ((size_t)src << 8) + voff8);
    uint2 Pn0 = es[umin_u(b0 + 2u * p + 2u, emax)];
    uint2 Pn1 = es[umin_u(b0 + 2u * p + 3u, emax)];

    const unsigned cb = eid * 128u + l31 * 4u;
    unsigned r0a, r0b, r1a, r1b, r2a, r2b, r3a, r3b;
    threefry2x32(k0, k1, 0u, cb + 0u, r0a, r0b);
    threefry2x32(k0, k1, 0u, cb + 1u, r1a, r1b);
    threefry2x32(k0, k1, 0u, cb + 2u, r2a, r2b);
    threefry2x32(k0, k1, 0u, cb + 3u, r3a, r3b);
    const float m0 = ((r0a ^ r0b) < KEEP_THR) ? (1.0f / 0.9f) : 0.f;
    const float m1 = ((r1a ^ r1b) < KEEP_THR) ? (1.0f / 0.9f) : 0.f;
    const float m2 = ((r2a ^ r2b) < KEEP_THR) ? (1.0f / 0.9f) : 0.f;
    const float m3 = ((r3a ^ r3b) < KEEP_THR) ? (1.0f / 0.9f) : 0.f;
    a0 = fmaf(__uint_as_float(g.x << 16), m0, a0);
    a1 = fmaf(__uint_as_float(g.x & 0xffff0000u), m1, a1);
    a2 = fmaf(__uint_as_float(g.y << 16), m2, a2);
    a3 = fmaf(__uint_as_float(g.y & 0xffff0000u), m3, a3);

    eA = __builtin_amdgcn_readfirstlane(Pn0.x);
    sA = __builtin_amdgcn_readfirstlane(Pn0.y);
    eB = __builtin_amdgcn_readfirstlane(Pn1.x);
    sB = __builtin_amdgcn_readfirstlane(Pn1.y);
  }

  if (odd) {
    const uint2 g = *reinterpret_cast<const uint2*>(
        reinterpret_cast<const char*>(proj) + ((size_t)sA << 8) + voff8);
    const unsigned cb = eA * 128u + l31 * 4u;
    unsigned r0a, r0b, r1a, r1b, r2a, r2b, r3a, r3b;
    threefry2x32(k0, k1, 0u, cb + 0u, r0a, r0b);
    threefry2x32(k0, k1, 0u, cb + 1u, r1a, r1b);
    threefry2x32(k0, k1, 0u, cb + 2u, r2a, r2b);
    threefry2x32(k0, k1, 0u, cb + 3u, r3a, r3b);
    const float sc = hi ? 0.f : (1.0f / 0.9f);
    const float m0 = ((r0a ^ r0b) < KEEP_THR) ? sc : 0.f;
    const float m1 = ((r1a ^ r1b) < KEEP_THR) ? sc : 0.f;
    const float m2 = ((r2a ^ r2b) < KEEP_THR) ? sc : 0.f;
    const float m3 = ((r3a ^ r3b) < KEEP_THR) ? sc : 0.f;
    a0 = fmaf(__uint_as_float(g.x << 16), m0, a0);
    a1 = fmaf(__uint_as_float(g.x & 0xffff0000u), m1, a1);
    a2 = fmaf(__uint_as_float(g.y << 16), m2, a2);
    a3 = fmaf(__uint_as_float(g.y & 0xffff0000u), m3, a3);
  }

  a0 += __shfl_xor(a0, 32);
  a1 += __shfl_xor(a1, 32);
  a2 += __shfl_xor(a2, 32);
  a3 += __shfl_xor(a3, 32);

  const float inv = 1.0f / fmaxf((float)n, 1.0f);
  const float u0 = hi ? a2 : a0;
  const float u1 = hi ? a3 : a1;
  const unsigned pk =
      ((unsigned)f2bf(u0 * inv)) | (((unsigned)f2bf(u1 * inv)) << 16);
  unsigned* out = reinterpret_cast<unsigned*>(accum_all) + (size_t)d * 64;
  out[2u * l31 + (hi ? 1u : 0u)] = pk;
}

// ---------------------------------------------------------------------------
extern "C" void kernel_launch(void* const* d_in, const int* in_sizes, int n_in,
                              void* d_out, int out_size, void* d_ws, size_t ws_size,
                              hipStream_t stream) {
  const float* x_user      = (const float*)d_in[0];
  const float* x_spot      = (const float*)d_in[1];
  const float* W_visit_src = (const float*)d_in[2];
  const float* W_visit_tgt = (const float*)d_in[3];
  const float* W_rev_src   = (const float*)d_in[4];
  const float* W_rev_tgt   = (const float*)d_in[5];
  const float* W_near_src  = (const float*)d_in[6];
  const float* W_near_tgt  = (const float*)d_in[7];
  const int* visit_src = (const int*)d_in[8];
  const int* visit_dst = (const int*)d_in[9];
  const int* rev_src   = (const int*)d_in[10];
  const int* rev_dst   = (const int*)d_in[11];
  const int* near_src  = (const int*)d_in[12];
  const int* near_dst  = (const int*)d_in[13];

  const int n_user = in_sizes[0] / DF;
  const int n_spot = in_sizes[1] / DF;
  const int e_visit = in_sizes[8];
  const int e_rev   = in_sizes[10];
  const int e_near  = in_sizes[12];

  float* out_user = (float*)d_out;
  float* out_spot = out_user + (size_t)n_user * DF;

  const int NT = n_spot + n_user + n_spot;
  const int segU = n_spot;
  const int segN = n_spot + n_user;
  const int etot = e_visit + e_rev + e_near;
  const unsigned emax = (unsigned)(etot - 1);

  // ---- workspace ----
  char* ws = (char*)d_ws;
  size_t off = 0;
  auto alloc = [&](size_t bytes) -> void* {
    void* p = ws + off;
    off += (bytes + 255) & ~(size_t)255;
    return p;
  };
  ushort_t* proj_vs   = (ushort_t*)alloc((size_t)n_user * DF * 2);
  ushort_t* proj_rs   = (ushort_t*)alloc((size_t)n_spot * DF * 2);
  ushort_t* proj_ns   = (ushort_t*)alloc((size_t)n_spot * DF * 2);
  ushort_t* accum_all = (ushort_t*)alloc((size_t)NT * DF * 2);
  uint2*    es_all    = (uint2*)   alloc((size_t)etot * 8);
  unsigned* rp_all    = (unsigned*)alloc(((size_t)NT + 1) * 4);
  unsigned* cur_all   = (unsigned*)alloc((size_t)NT * 4);
  unsigned* deg_all   = (unsigned*)alloc((size_t)NT * 4);
  unsigned* done      = (unsigned*)alloc(256);    // done[0]=counter, done[1]=flag
  unsigned* bsum      = (unsigned*)alloc(4096);   // not zeroed (fully written)
  unsigned* bsumX     = (unsigned*)alloc(4096);
  char* zero_end = (char*)bsum;   // memset deg_all..done (contiguous)

  ushort_t* mean_sv = accum_all;
  ushort_t* mean_u  = accum_all + (size_t)segU * DF;
  ushort_t* mean_sn = accum_all + (size_t)segN * DF;

  unsigned kv0, kv1, kr0, kr1, kn0, kn1;
  threefry2x32(0u, 1u, 0u, 0u, kv0, kv1);
  threefry2x32(0u, 1u, 0u, 1u, kr0, kr1);
  threefry2x32(0u, 1u, 0u, 2u, kn0, kn1);

  dim3 blk(256);
  const int gbU = (n_user + 127) / 128;
  const int gbS = (n_spot + 127) / 128;
  const int gb_e = (etot + 255) / 256;
  const int nb_scan = (NT + SCAN_E - 1) / SCAN_E;
  const int gemmBlocks = gbU + 2 * gbS;

  // zero deg_all + done counters (contiguous region)
  hipMemsetAsync(deg_all, 0, (size_t)(zero_end - (char*)deg_all), stream);

  // fused: 3 projection GEMMs + edge histogram (overlapping block roles)
  proj3_hist<<<gemmBlocks + gb_e, blk, 0, stream>>>(
      x_user, x_spot, W_visit_src, W_rev_src, W_near_src,
      n_user, n_spot, proj_vs, proj_rs, proj_ns, gbU, gbS,
      visit_dst, rev_dst, near_dst, deg_all,
      e_visit, e_rev, e_near, segU, segN, gemmBlocks);

  // single-kernel 2-level scan -> rowptr + cursors
  scanABC<<<nb_scan, blk, 0, stream>>>(deg_all, bsum, bsumX, rp_all, cur_all,
                                       done, NT, nb_scan);
  fill3<<<gb_e, blk, 0, stream>>>(visit_src, visit_dst, rev_src, rev_dst,
                                  near_src, near_dst, cur_all, es_all,
                                  e_visit, e_rev, e_near, segU, segN);

  // fused gather-reduce over all NT rows
  gather_reduce_all<<<(NT + 3) / 4, blk, 0, stream>>>(
      proj_vs, proj_rs, proj_ns, es_all, rp_all, accum_all,
      NT, segU, segN, emax, kv0, kv1, kr0, kr1, kn0, kn1);

  // fused finalize
  final2_gemm<<<gbU + gbS, blk, 0, stream>>>(
      x_user, x_spot, W_rev_tgt, W_visit_tgt, W_near_tgt,
      n_user, n_spot, out_user, out_spot, mean_u, mean_sv, mean_sn, gbU);
}